// Round 15
// baseline (317.614 us; speedup 1.0000x reference)
//
#include <hip/hip_runtime.h>
#include <hip/hip_bf16.h>
#include <math.h>

using bf16 = __hip_bfloat16;
typedef short bfrag __attribute__((ext_vector_type(8)));
typedef float f32x4 __attribute__((ext_vector_type(4)));

__device__ __forceinline__ float b2f(bf16 v){ return __bfloat162float(v); }
__device__ __forceinline__ bf16  f2b(float v){ return __float2bfloat16(v); }
__device__ __forceinline__ short f2bs(float v){ bf16 t = f2b(v); union{bf16 h; short s;} u; u.h = t; return u.s; }
__device__ __forceinline__ float bits2f(unsigned short s){ union{unsigned u; float f;} c; c.u = ((unsigned)s) << 16; return c.f; }
__device__ __forceinline__ int   pk2(float lo, float hi){
  return (((int)(unsigned short)f2bs(hi)) << 16) | (int)(unsigned short)f2bs(lo);
}
__device__ __forceinline__ float ldT(const float* p, long long i){ return p[i]; }
__device__ __forceinline__ float ldT(const bf16*  p, long long i){ return __bfloat162float(p[i]); }

__device__ __forceinline__ bfrag ldfrag(const bf16* p){ return *reinterpret_cast<const bfrag*>(p); }
__device__ __forceinline__ f32x4 mm16(bfrag a, bfrag b, f32x4 c){
  return __builtin_amdgcn_mfma_f32_16x16x32_bf16(a, b, c, 0, 0, 0);
}
// async global->LDS DMA, 16B/lane: lds dest = uniform base + lane*16
__device__ __forceinline__ void gload_lds16(const void* g, void* l){
  __builtin_amdgcn_global_load_lds(
    (const __attribute__((address_space(1))) unsigned int*)g,
    (__attribute__((address_space(3))) unsigned int*)l, 16, 0, 0);
}

// ---- fast cross-lane reductions via DPP ----
template<int CTRL>
__device__ __forceinline__ float dppf(float v){
  union{float f; int i;} u; u.f = v;
  u.i = __builtin_amdgcn_update_dpp(0, u.i, CTRL, 0xF, 0xF, true);
  return u.f;
}
__device__ __forceinline__ float rmax16(float v){
  v = fmaxf(v, dppf<0xB1>(v));  v = fmaxf(v, dppf<0x4E>(v));
  v = fmaxf(v, dppf<0x141>(v)); v = fmaxf(v, dppf<0x140>(v));
  return v;
}
__device__ __forceinline__ float rsum16(float v){
  v += dppf<0xB1>(v);  v += dppf<0x4E>(v);
  v += dppf<0x141>(v); v += dppf<0x140>(v);
  return v;
}
__device__ __forceinline__ float rsum4(float v){
  v += dppf<0xB1>(v); v += dppf<0x4E>(v);
  return v;
}

// post-shift region id along one axis (H=W=256, ws=8, shift=4)
__device__ __forceinline__ int reg1(int g){ return (g >= 248) + (g >= 252); }
// window-token -> natural token index (cyclic-shift reverse)
__device__ __forceinline__ long long natidx(int gw, int t){
  const int wl = gw & 1023;
  const int sr = (((wl >> 5) << 3) + (t >> 3) + 4) & 255;
  const int sc = (((wl & 31) << 3) + (t & 7) + 4) & 255;
  return (((long long)(gw >> 10)) << 16) + sr*256 + sc;
}

// load 48 consecutive values (f32 or bf16) to float regs
template<typename T>
__device__ __forceinline__ void ld48(const T* p, long long off, float* d){
  if constexpr (sizeof(T) == 4){
    #pragma unroll
    for (int i = 0; i < 12; ++i){
      float4 v = *reinterpret_cast<const float4*>((const float*)p + off + i*4);
      d[i*4+0]=v.x; d[i*4+1]=v.y; d[i*4+2]=v.z; d[i*4+3]=v.w;
    }
  } else {
    #pragma unroll
    for (int i = 0; i < 6; ++i){
      bfrag v = *reinterpret_cast<const bfrag*>((const bf16*)p + off + i*8);
      #pragma unroll
      for (int j = 0; j < 8; ++j) d[i*8+j] = bits2f((unsigned short)v[j]);
    }
  }
}

// ---- workspace layout (bytes) ----
#define WS_QKV   0
#define WS_PROJ  221184
#define WS_FC1   294912
#define WS_FC2   589824
#define WS_BIAS6 884736

// ================= prep: repack weights frag-major bf16 + bias table =========
__global__ __launch_bounds__(256) void prep_k(const void* det,
    const void* qkvw, const void* projw, const void* fc1w, const void* fc2w,
    const void* rpb, const int* __restrict__ relidx, char* wsb)
{
  const bool isbf = (((const unsigned short*)det)[0] == 0x3F80u);
  const int gt = blockIdx.x * 256 + threadIdx.x;
  if (gt < 55296) {
    const int fid = gt >> 6, l = gt & 63;
    int f, nkt, ckw; const void* src; bf16* dst;
    if (fid < 216)      { f = fid;       nkt = 6;  ckw = 192; src = qkvw;  dst = (bf16*)(wsb + WS_QKV); }
    else if (fid < 288) { f = fid - 216; nkt = 6;  ckw = 192; src = projw; dst = (bf16*)(wsb + WS_PROJ); }
    else if (fid < 576) { f = fid - 288; nkt = 6;  ckw = 192; src = fc1w;  dst = (bf16*)(wsb + WS_FC1); }
    else                { f = fid - 576; nkt = 24; ckw = 768; src = fc2w;  dst = (bf16*)(wsb + WS_FC2); }
    const int ct = f / nkt, kt = f - ct * nkt;
    const long long ro = (long long)(ct*16 + (l & 15)) * ckw + kt*32 + (l >> 4)*8;
    bf16* dp = dst + ((long long)f * 64 + l) * 8;
    #pragma unroll
    for (int j = 0; j < 8; ++j) {
      float v = isbf ? b2f(((const bf16*)src)[ro + j]) : ((const float*)src)[ro + j];
      dp[j] = f2b(v);
    }
  } else if (gt < 55296 + 24576) {
    const int t = gt - 55296;
    const int h = t >> 12, ij = t & 4095;
    const int ri = relidx[ij];
    float v = isbf ? b2f(((const bf16*)rpb)[ri*6 + h]) : ((const float*)rpb)[ri*6 + h];
    ((float*)(wsb + WS_BIAS6))[t] = v;
  }
}

// ===== K1 fused attn+proj: 1 window/block, 4 waves, x2 -> d_out slots ========
#define XN_S 200
#define QK_S 72
#define VT_S 72
#define LDS_K1 (64*XN_S*2 + 64*QK_S*2 + 32*VT_S*2)   // 25600+9216+4608 = 39424 B

template<typename T>
__device__ void attn_body(const T* __restrict__ x, const T* __restrict__ g1, const T* __restrict__ b1,
                          const bf16* __restrict__ qkvwp, const T* __restrict__ qkvb,
                          const bf16* __restrict__ projwp, const T* __restrict__ projb,
                          const float* __restrict__ bias6, char* __restrict__ dout,
                          int x2f32, char* smem)
{
  bf16* xn = (bf16*)smem;            // [64][200]: LN out -> (cols 0-63 own rows) P -> oh
  bf16* qk = xn + 64*XN_S;           // [64][72]: Q cols 0-31, K cols 32-63
  bf16* vt = qk + 64*QK_S;           // [32][72]: V^T
  const int tid = threadIdx.x, l = tid & 63, w = tid >> 6;   // w = 0..3
  const int lr = l & 15, lg = l >> 4;
  const int gw = blockIdx.x;
  const int wl = gw & 1023, wi = wl >> 5, wj = wl & 31;

  // ---- LN1: 16 own-wave tokens, 4 lanes/token, quad-DPP reduce ----
  {
    const int t = (w << 4) + (l >> 2);
    const int c0 = (l & 3) * 48;
    const long long base = natidx(gw, t) * 192 + c0;
    float xv[48];
    ld48(x, base, xv);
    float s1 = 0.f, s2 = 0.f;
    #pragma unroll
    for (int i = 0; i < 48; ++i){ s1 += xv[i]; s2 = fmaf(xv[i], xv[i], s2); }
    s1 = rsum4(s1); s2 = rsum4(s2);
    const float m  = s1 * (1.f/192.f);
    const float rs = rsqrtf(s2*(1.f/192.f) - m*m + 1e-5f);
    bf16* xr = xn + t*XN_S + c0;
    #pragma unroll
    for (int cb = 0; cb < 6; ++cb){
      bfrag o;
      #pragma unroll
      for (int j = 0; j < 8; ++j){
        const int c = cb*8 + j;
        o[j] = f2bs((xv[c]-m)*rs*ldT(g1, c0+c) + ldT(b1, c0+c));
      }
      *reinterpret_cast<bfrag*>(xr + cb*8) = o;
    }
  }
  // LN wrote own-wave rows; xa hoist reads own-wave rows -> wave-internal, no barrier.

  // ---- A-fragments to registers (xn then dead during head loop) ----
  bfrag xa[6];
  #pragma unroll
  for (int kt = 0; kt < 6; ++kt)
    xa[kt] = ldfrag(&xn[(w*16 + lr)*XN_S + kt*32 + lg*8]);

  // ---- mask class ids (row-class*3 + col-class), packed ----
  int cj[4], ci[4];
  #pragma unroll
  for (int ct = 0; ct < 4; ++ct){
    const int j = ct*16 + lr;
    cj[ct] = reg1(wi*8 + (j >> 3))*3 + reg1(wj*8 + (j & 7));
  }
  #pragma unroll
  for (int r = 0; r < 4; ++r){
    const int i = w*16 + lg*4 + r;
    ci[r] = reg1(wi*8 + (i >> 3))*3 + reg1(wj*8 + (i & 7));
  }

  int ohpk[6][2][2];

  // ---- QKV for head 0 (A regs, B from L2; no LDS) ----
  f32x4 acc[6];
  #pragma unroll
  for (int u = 0; u < 6; ++u) acc[u] = (f32x4){0.f,0.f,0.f,0.f};
  #pragma unroll
  for (int kt = 0; kt < 6; ++kt){
    bfrag bq[6];
    #pragma unroll
    for (int u = 0; u < 6; ++u){
      const int ctg = (u >> 1)*12 + (u & 1);          // head 0
      bq[u] = ldfrag(qkvwp + ((long long)(ctg*6 + kt)*64 + l)*8);
    }
    #pragma unroll
    for (int u = 0; u < 6; ++u) acc[u] = mm16(xa[kt], bq[u], acc[u]);
  }

  #pragma unroll
  for (int h = 0; h < 6; ++h){
    __syncthreads();                 // A: all waves' prev QKT/PV reads of qk/vt done
    // ---- store head-h QKV: Q (scaled) | K -> qk, V^T -> vt ----
    #pragma unroll
    for (int u = 0; u < 6; ++u){
      const int ctg = (u >> 1)*12 + 2*h + (u & 1);
      const float bia = ldT(qkvb, ctg*16 + lr);
      #pragma unroll
      for (int r = 0; r < 4; ++r){
        const int row = w*16 + lg*4 + r;
        const float v = acc[u][r] + bia;
        if (u < 2)      qk[row*QK_S + u*16 + lr] = f2b(v * 0.17677669529663687f);
        else if (u < 4) qk[row*QK_S + 32 + (u & 1)*16 + lr] = f2b(v);
        else            vt[((u & 1)*16 + lr)*VT_S + row] = f2b(v);
      }
    }
    __syncthreads();                 // B: qk/vt visible to all waves

    // ---- issue next head's QKV (overlaps QKT/softmax/PV below) ----
    if (h < 5){
      #pragma unroll
      for (int u = 0; u < 6; ++u) acc[u] = (f32x4){0.f,0.f,0.f,0.f};
      #pragma unroll
      for (int kt = 0; kt < 6; ++kt){
        bfrag bq[6];
        #pragma unroll
        for (int u = 0; u < 6; ++u){
          const int ctg = (u >> 1)*12 + 2*(h+1) + (u & 1);
          bq[u] = ldfrag(qkvwp + ((long long)(ctg*6 + kt)*64 + l)*8);
        }
        #pragma unroll
        for (int u = 0; u < 6; ++u) acc[u] = mm16(xa[kt], bq[u], acc[u]);
      }
    }

    // ---- QK^T ----
    f32x4 s4[4];
    {
      bfrag aq = ldfrag(&qk[(w*16 + lr)*QK_S + lg*8]);
      #pragma unroll
      for (int ct = 0; ct < 4; ++ct)
        s4[ct] = mm16(aq, ldfrag(&qk[(ct*16 + lr)*QK_S + 32 + lg*8]), (f32x4){0.f,0.f,0.f,0.f});
    }
    // ---- bias + mask + softmax; P -> xn (own rows, cols 0-63) ----
    const float* bh = bias6 + h*4096;
    #pragma unroll
    for (int r = 0; r < 4; ++r){
      const int i = w*16 + lg*4 + r;
      const int ib = i*64 + lr;
      float v[4];
      #pragma unroll
      for (int ct = 0; ct < 4; ++ct){
        const float msk = (ci[r] == cj[ct]) ? 0.f : -100.f;
        v[ct] = s4[ct][r] + bh[ib + ct*16] + msk;
      }
      float mx = rmax16(fmaxf(fmaxf(v[0],v[1]), fmaxf(v[2],v[3])));
      v[0] = __expf(v[0]-mx); v[1] = __expf(v[1]-mx);
      v[2] = __expf(v[2]-mx); v[3] = __expf(v[3]-mx);
      const float sm = rsum16(v[0]+v[1]+v[2]+v[3]);
      const float inv = __fdividef(1.f, sm);
      #pragma unroll
      for (int ct = 0; ct < 4; ++ct)
        xn[i*XN_S + ct*16 + lr] = f2b(v[ct]*inv);
    }
    // ---- PV (P own rows from xn; vt all rows, stored pre-B) ----
    f32x4 o2[2] = {(f32x4){0.f,0.f,0.f,0.f}, (f32x4){0.f,0.f,0.f,0.f}};
    #pragma unroll
    for (int ktp = 0; ktp < 2; ++ktp){
      bfrag ap = ldfrag(&xn[(w*16 + lr)*XN_S + ktp*32 + lg*8]);
      o2[0] = mm16(ap, ldfrag(&vt[(lr)*VT_S + ktp*32 + lg*8]), o2[0]);
      o2[1] = mm16(ap, ldfrag(&vt[(16 + lr)*VT_S + ktp*32 + lg*8]), o2[1]);
    }
    #pragma unroll
    for (int u = 0; u < 2; ++u){
      ohpk[h][u][0] = pk2(o2[u][0], o2[u][1]);
      ohpk[h][u][1] = pk2(o2[u][2], o2[u][3]);
    }
  }

  // ---- oh -> xn region (own rows; P dead) ----
  #pragma unroll
  for (int h = 0; h < 6; ++h)
    #pragma unroll
    for (int u = 0; u < 2; ++u)
      #pragma unroll
      for (int rr = 0; rr < 2; ++rr){
        const int pk = ohpk[h][u][rr];
        const int row = w*16 + lg*4 + rr*2;
        *reinterpret_cast<short*>(&xn[row*XN_S + h*32 + u*16 + lr]) = (short)(pk & 0xffff);
        *reinterpret_cast<short*>(&xn[(row+1)*XN_S + h*32 + u*16 + lr]) = (short)(((unsigned)pk) >> 16);
      }
  __syncthreads();                   // oh visible to all waves

  // ---- proj: wave -> (mp rows 32, chh 6 ct), K=192, B from L2 ----
  const int mp = w >> 1, chh = w & 1;
  f32x4 pacc[2][6];
  #pragma unroll
  for (int mt = 0; mt < 2; ++mt)
    #pragma unroll
    for (int cc = 0; cc < 6; ++cc) pacc[mt][cc] = (f32x4){0.f,0.f,0.f,0.f};
  #pragma unroll
  for (int kt = 0; kt < 6; ++kt){
    bfrag a0 = ldfrag(&xn[(mp*32 + lr)*XN_S + kt*32 + lg*8]);
    bfrag a1 = ldfrag(&xn[(mp*32 + 16 + lr)*XN_S + kt*32 + lg*8]);
    #pragma unroll
    for (int cc = 0; cc < 6; ++cc){
      bfrag bp = ldfrag(projwp + ((long long)((chh*6 + cc)*6 + kt)*64 + l)*8);
      pacc[0][cc] = mm16(a0, bp, pacc[0][cc]);
      pacc[1][cc] = mm16(a1, bp, pacc[1][cc]);
    }
  }
  // ---- epilogue: bias + residual + x2 store ----
  #pragma unroll
  for (int mt = 0; mt < 2; ++mt)
    #pragma unroll
    for (int r = 0; r < 4; ++r){
      const int t = mp*32 + mt*16 + lg*4 + r;
      const long long n = natidx(gw, t);
      #pragma unroll
      for (int cc = 0; cc < 6; ++cc){
        const int c = (chh*6 + cc)*16 + lr;
        const float y = pacc[mt][cc][r] + ldT(projb, c) + ldT(x, n*192 + c);
        if (x2f32) ((float*)(dout + n*768))[c] = y;
        else       ((bf16*)(dout + n*384))[c]  = f2b(y);
      }
    }
}

__global__ __launch_bounds__(256, 4) void swin_attn_k(
    const void* det, const void* x, const void* g1, const void* b1,
    const bf16* qkvwp, const void* qkvb, const bf16* projwp, const void* projb,
    const float* bias6, void* doutv)
{
  extern __shared__ char smem[];
  const bool isbf = (((const unsigned short*)det)[0] == 0x3F80u);
  char* dout = (char*)doutv;
  if (isbf)
    attn_body<bf16>((const bf16*)x, (const bf16*)g1, (const bf16*)b1, qkvwp,
                    (const bf16*)qkvb, projwp, (const bf16*)projb, bias6, dout, 0, smem);
  else
    attn_body<float>((const float*)x, (const float*)g1, (const float*)b1, qkvwp,
                     (const float*)qkvb, projwp, (const float*)projb, bias6, dout, 1, smem);
}

// ========== K3 MLP: 128 tokens/block, 4 waves, 12 chunks of 64 hidden ========
#define HS_S 72
#define LDS_K3 (48*512*2 + 128*HS_S*2)    // 49152 + 18432 = 67584 (xn2 51.2KB unioned)

template<typename T>
__device__ void mlp_body(const T* __restrict__ g2, const T* __restrict__ b2,
                         const bf16* __restrict__ fc1p, const T* __restrict__ fb1,
                         const bf16* __restrict__ fc2p, const T* __restrict__ fb2,
                         char* __restrict__ dout, int outf32, char* smem)
{
  bf16* xn2 = (bf16*)smem;            // [128][200] prologue only
  bf16* bw  = (bf16*)smem;            // [48*512] chunk weights
  bf16* hs  = bw + 48*512;            // [128][72]
  const int tid = threadIdx.x, l = tid & 63, w = tid >> 6;
  const int lr = l & 15, lg = l >> 4;
  const long long t0 = (long long)blockIdx.x * 128;

  // ---- LN2 on x2 slots (2 iters x 16 tokens/wave, quad-DPP) ----
  #pragma unroll
  for (int it = 0; it < 2; ++it){
    const int t = w*32 + it*16 + (l >> 2);
    const int c0 = (l & 3) * 48;
    const long long n = t0 + t;
    float xv[48];
    if (outf32) ld48((const float*)(dout + n*768), c0, xv);
    else        ld48((const bf16*)(dout + n*384), c0, xv);
    float s1 = 0.f, s2 = 0.f;
    #pragma unroll
    for (int i = 0; i < 48; ++i){ s1 += xv[i]; s2 = fmaf(xv[i], xv[i], s2); }
    s1 = rsum4(s1); s2 = rsum4(s2);
    const float m  = s1 * (1.f/192.f);
    const float rs = rsqrtf(s2*(1.f/192.f) - m*m + 1e-5f);
    bf16* xr = xn2 + t*XN_S + c0;
    #pragma unroll
    for (int cb = 0; cb < 6; ++cb){
      bfrag o;
      #pragma unroll
      for (int j = 0; j < 8; ++j){
        const int c = cb*8 + j;
        o[j] = f2bs((xv[c]-m)*rs*ldT(g2, c0+c) + ldT(b2, c0+c));
      }
      *reinterpret_cast<bfrag*>(xr + cb*8) = o;
    }
  }
  __syncthreads();

  bfrag xa[2][6];
  #pragma unroll
  for (int mt = 0; mt < 2; ++mt)
    #pragma unroll
    for (int kt = 0; kt < 6; ++kt)
      xa[mt][kt] = ldfrag(&xn2[(w*32 + mt*16 + lr)*XN_S + kt*32 + lg*8]);
  __syncthreads();                     // xn2 dead -> bw/hs region free

  f32x4 fa[2][12];
  #pragma unroll
  for (int mt = 0; mt < 2; ++mt)
    #pragma unroll
    for (int ct = 0; ct < 12; ++ct) fa[mt][ct] = (f32x4){0.f,0.f,0.f,0.f};

  for (int c = 0; c < 12; ++c){
    // ---- stage 48 frags (12/wave) via async global->LDS DMA, 0 VGPRs ----
    {
      const int q0 = w*12;
      #pragma unroll
      for (int e = 0; e < 12; ++e){
        const int q = q0 + e;
        const bf16* src = (q < 24)
          ? fc1p + ((long long)(c*24 + q)*64 + l)*8
          : fc2p + ((long long)(((q-24) >> 1)*24 + c*2 + ((q-24) & 1))*64 + l)*8;
        gload_lds16(src, bw + q*512);   // dst byte = q*1024 + lane*16
      }
    }
    __syncthreads();                    // drains vmcnt -> bw ready
    // fc1 (48 MFMA)
    f32x4 a1[2][4];
    #pragma unroll
    for (int mt = 0; mt < 2; ++mt)
      #pragma unroll
      for (int u = 0; u < 4; ++u) a1[mt][u] = (f32x4){0.f,0.f,0.f,0.f};
    #pragma unroll
    for (int kt = 0; kt < 6; ++kt)
      #pragma unroll
      for (int u = 0; u < 4; ++u){
        bfrag bq = ldfrag(&bw[((u*6 + kt)*64 + l)*8]);
        a1[0][u] = mm16(xa[0][kt], bq, a1[0][u]);
        a1[1][u] = mm16(xa[1][kt], bq, a1[1][u]);
      }
    // bias + GELU(sigmoid) -> hs (wave-private rows)
    #pragma unroll
    for (int u = 0; u < 4; ++u){
      const float bia = ldT(fb1, c*64 + u*16 + lr);
      #pragma unroll
      for (int mt = 0; mt < 2; ++mt)
        #pragma unroll
        for (int r = 0; r < 4; ++r){
          const float xv = a1[mt][u][r] + bia;
          const float g  = __fdividef(xv, 1.f + __expf(-1.702f*xv));
          hs[(w*32 + mt*16 + lg*4 + r)*HS_S + u*16 + lr] = f2b(g);
        }
    }
    // fc2 (48 MFMA)
    #pragma unroll
    for (int ktl = 0; ktl < 2; ++ktl){
      bfrag aH0 = ldfrag(&hs[(w*32 + lr)*HS_S + ktl*32 + lg*8]);
      bfrag aH1 = ldfrag(&hs[(w*32 + 16 + lr)*HS_S + ktl*32 + lg*8]);
      #pragma unroll
      for (int ct = 0; ct < 12; ++ct){
        bfrag bq = ldfrag(&bw[((24 + ct*2 + ktl)*64 + l)*8]);
        fa[0][ct] = mm16(aH0, bq, fa[0][ct]);
        fa[1][ct] = mm16(aH1, bq, fa[1][ct]);
      }
    }
    __syncthreads();                   // bw reads done before next stage
  }

  // ---- epilogue: + fb2 + residual(x2 slot) -> final out (in-place) ----
  #pragma unroll
  for (int mt = 0; mt < 2; ++mt)
    #pragma unroll
    for (int r = 0; r < 4; ++r){
      const long long n = t0 + w*32 + mt*16 + lg*4 + r;
      #pragma unroll
      for (int ct = 0; ct < 12; ++ct){
        const int cc = ct*16 + lr;
        float resid = outf32 ? ((const float*)(dout + n*768))[cc]
                             : b2f(((const bf16*)(dout + n*384))[cc]);
        const float y = fa[mt][ct][r] + ldT(fb2, cc) + resid;
        if (outf32) ((float*)(dout + n*768))[cc] = y;
        else        ((bf16*)(dout + n*384))[cc]  = f2b(y);
      }
    }
}

__global__ __launch_bounds__(256, 2) void swin_mlp_k(
    const void* det, const void* g2, const void* b2, const bf16* fc1p, const void* fb1,
    const bf16* fc2p, const void* fb2, void* doutv)
{
  extern __shared__ char smem[];
  const bool isbf = (((const unsigned short*)det)[0] == 0x3F80u);
  char* dout = (char*)doutv;
  if (isbf)
    mlp_body<bf16>((const bf16*)g2, (const bf16*)b2, fc1p, (const bf16*)fb1,
                   fc2p, (const bf16*)fb2, dout, 0, smem);
  else
    mlp_body<float>((const float*)g2, (const float*)b2, fc1p, (const float*)fb1,
                    fc2p, (const float*)fb2, dout, 1, smem);
}

extern "C" void kernel_launch(void* const* d_in, const int* in_sizes, int n_in,
                              void* d_out, int out_size, void* d_ws, size_t ws_size,
                              hipStream_t stream)
{
  (void)in_sizes; (void)n_in; (void)out_size; (void)ws_size;
  char* ws = (char*)d_ws;

  (void)hipFuncSetAttribute((const void*)swin_attn_k, hipFuncAttributeMaxDynamicSharedMemorySize, LDS_K1);
  (void)hipFuncSetAttribute((const void*)swin_mlp_k,  hipFuncAttributeMaxDynamicSharedMemorySize, LDS_K3);

  prep_k<<<dim3(312), dim3(256), 0, stream>>>(
      d_in[1], d_in[3], d_in[6], d_in[10], d_in[12], d_in[5], (const int*)d_in[15], ws);

  swin_attn_k<<<dim3(2048), dim3(256), LDS_K1, stream>>>(
      d_in[1], d_in[0], d_in[1], d_in[2],
      (const bf16*)(ws + WS_QKV), d_in[4], (const bf16*)(ws + WS_PROJ), d_in[7],
      (const float*)(ws + WS_BIAS6), d_out);

  swin_mlp_k<<<dim3(1024), dim3(256), LDS_K3, stream>>>(
      d_in[1], d_in[8], d_in[9],
      (const bf16*)(ws + WS_FC1), d_in[11], (const bf16*)(ws + WS_FC2), d_in[13], d_out);
}

// Round 16
// 288.990 us; speedup vs baseline: 1.0991x; 1.0991x over previous
//
#include <hip/hip_runtime.h>
#include <hip/hip_bf16.h>
#include <math.h>

using bf16 = __hip_bfloat16;
typedef short bfrag __attribute__((ext_vector_type(8)));
typedef float f32x4 __attribute__((ext_vector_type(4)));

__device__ __forceinline__ float b2f(bf16 v){ return __bfloat162float(v); }
__device__ __forceinline__ bf16  f2b(float v){ return __float2bfloat16(v); }
__device__ __forceinline__ short f2bs(float v){ bf16 t = f2b(v); union{bf16 h; short s;} u; u.h = t; return u.s; }
__device__ __forceinline__ float bits2f(unsigned short s){ union{unsigned u; float f;} c; c.u = ((unsigned)s) << 16; return c.f; }
__device__ __forceinline__ int   pk2(float lo, float hi){
  return (((int)(unsigned short)f2bs(hi)) << 16) | (int)(unsigned short)f2bs(lo);
}
__device__ __forceinline__ float ldT(const float* p, long long i){ return p[i]; }
__device__ __forceinline__ float ldT(const bf16*  p, long long i){ return __bfloat162float(p[i]); }

__device__ __forceinline__ bfrag ldfrag(const bf16* p){ return *reinterpret_cast<const bfrag*>(p); }
__device__ __forceinline__ f32x4 mm16(bfrag a, bfrag b, f32x4 c){
  return __builtin_amdgcn_mfma_f32_16x16x32_bf16(a, b, c, 0, 0, 0);
}
// async global->LDS DMA, 16B/lane: lds dest = uniform base + lane*16
__device__ __forceinline__ void gload_lds16(const void* g, void* l){
  __builtin_amdgcn_global_load_lds(
    (const __attribute__((address_space(1))) unsigned int*)g,
    (__attribute__((address_space(3))) unsigned int*)l, 16, 0, 0);
}

// ---- fast cross-lane reductions via DPP ----
template<int CTRL>
__device__ __forceinline__ float dppf(float v){
  union{float f; int i;} u; u.f = v;
  u.i = __builtin_amdgcn_update_dpp(0, u.i, CTRL, 0xF, 0xF, true);
  return u.f;
}
__device__ __forceinline__ float rmax16(float v){
  v = fmaxf(v, dppf<0xB1>(v));  v = fmaxf(v, dppf<0x4E>(v));
  v = fmaxf(v, dppf<0x141>(v)); v = fmaxf(v, dppf<0x140>(v));
  return v;
}
__device__ __forceinline__ float rsum16(float v){
  v += dppf<0xB1>(v);  v += dppf<0x4E>(v);
  v += dppf<0x141>(v); v += dppf<0x140>(v);
  return v;
}
__device__ __forceinline__ float rsum4(float v){
  v += dppf<0xB1>(v); v += dppf<0x4E>(v);
  return v;
}

// post-shift region id along one axis (H=W=256, ws=8, shift=4)
__device__ __forceinline__ int reg1(int g){ return (g >= 248) + (g >= 252); }
// window-token -> natural token index (cyclic-shift reverse)
__device__ __forceinline__ long long natidx(int gw, int t){
  const int wl = gw & 1023;
  const int sr = (((wl >> 5) << 3) + (t >> 3) + 4) & 255;
  const int sc = (((wl & 31) << 3) + (t & 7) + 4) & 255;
  return (((long long)(gw >> 10)) << 16) + sr*256 + sc;
}

// load 48 consecutive values (f32 or bf16) to float regs
template<typename T>
__device__ __forceinline__ void ld48(const T* p, long long off, float* d){
  if constexpr (sizeof(T) == 4){
    #pragma unroll
    for (int i = 0; i < 12; ++i){
      float4 v = *reinterpret_cast<const float4*>((const float*)p + off + i*4);
      d[i*4+0]=v.x; d[i*4+1]=v.y; d[i*4+2]=v.z; d[i*4+3]=v.w;
    }
  } else {
    #pragma unroll
    for (int i = 0; i < 6; ++i){
      bfrag v = *reinterpret_cast<const bfrag*>((const bf16*)p + off + i*8);
      #pragma unroll
      for (int j = 0; j < 8; ++j) d[i*8+j] = bits2f((unsigned short)v[j]);
    }
  }
}

// ---- workspace layout (bytes) ----
#define WS_QKV   0
#define WS_PROJ  221184
#define WS_FC1   294912
#define WS_FC2   589824
#define WS_BIAS6 884736

// ================= prep: repack weights frag-major bf16 + bias table =========
__global__ __launch_bounds__(256) void prep_k(const void* det,
    const void* qkvw, const void* projw, const void* fc1w, const void* fc2w,
    const void* rpb, const int* __restrict__ relidx, char* wsb)
{
  const bool isbf = (((const unsigned short*)det)[0] == 0x3F80u);
  const int gt = blockIdx.x * 256 + threadIdx.x;
  if (gt < 55296) {
    const int fid = gt >> 6, l = gt & 63;
    int f, nkt, ckw; const void* src; bf16* dst;
    if (fid < 216)      { f = fid;       nkt = 6;  ckw = 192; src = qkvw;  dst = (bf16*)(wsb + WS_QKV); }
    else if (fid < 288) { f = fid - 216; nkt = 6;  ckw = 192; src = projw; dst = (bf16*)(wsb + WS_PROJ); }
    else if (fid < 576) { f = fid - 288; nkt = 6;  ckw = 192; src = fc1w;  dst = (bf16*)(wsb + WS_FC1); }
    else                { f = fid - 576; nkt = 24; ckw = 768; src = fc2w;  dst = (bf16*)(wsb + WS_FC2); }
    const int ct = f / nkt, kt = f - ct * nkt;
    const long long ro = (long long)(ct*16 + (l & 15)) * ckw + kt*32 + (l >> 4)*8;
    bf16* dp = dst + ((long long)f * 64 + l) * 8;
    #pragma unroll
    for (int j = 0; j < 8; ++j) {
      float v = isbf ? b2f(((const bf16*)src)[ro + j]) : ((const float*)src)[ro + j];
      dp[j] = f2b(v);
    }
  } else if (gt < 55296 + 24576) {
    const int t = gt - 55296;
    const int h = t >> 12, ij = t & 4095;
    const int ri = relidx[ij];
    float v = isbf ? b2f(((const bf16*)rpb)[ri*6 + h]) : ((const float*)rpb)[ri*6 + h];
    ((float*)(wsb + WS_BIAS6))[t] = v;
  }
}

// ===== K1 fused attn+proj: 1 window/block, 4 waves, x2 -> d_out slots ========
#define XN_S 200
#define QK_S 72
#define VT_S 72
#define LDS_K1 (64*XN_S*2 + 64*QK_S*2 + 32*VT_S*2)   // 25600+9216+4608 = 39424 B

template<typename T>
__device__ void attn_body(const T* __restrict__ x, const T* __restrict__ g1, const T* __restrict__ b1,
                          const bf16* __restrict__ qkvwp, const T* __restrict__ qkvb,
                          const bf16* __restrict__ projwp, const T* __restrict__ projb,
                          const float* __restrict__ bias6, char* __restrict__ dout,
                          int x2f32, char* smem)
{
  bf16* xn = (bf16*)smem;            // [64][200]: LN out -> (cols 0-63 own rows) P -> oh
  bf16* qk = xn + 64*XN_S;           // [64][72]: Q cols 0-31, K cols 32-63
  bf16* vt = qk + 64*QK_S;           // [32][72]: V^T
  const int tid = threadIdx.x, l = tid & 63, w = tid >> 6;   // w = 0..3
  const int lr = l & 15, lg = l >> 4;
  const int gw = blockIdx.x;
  const int wl = gw & 1023, wi = wl >> 5, wj = wl & 31;

  // ---- LN1: 16 own-wave tokens, 4 lanes/token, quad-DPP reduce ----
  {
    const int t = (w << 4) + (l >> 2);
    const int c0 = (l & 3) * 48;
    const long long base = natidx(gw, t) * 192 + c0;
    float xv[48];
    ld48(x, base, xv);
    float s1 = 0.f, s2 = 0.f;
    #pragma unroll
    for (int i = 0; i < 48; ++i){ s1 += xv[i]; s2 = fmaf(xv[i], xv[i], s2); }
    s1 = rsum4(s1); s2 = rsum4(s2);
    const float m  = s1 * (1.f/192.f);
    const float rs = rsqrtf(s2*(1.f/192.f) - m*m + 1e-5f);
    bf16* xr = xn + t*XN_S + c0;
    #pragma unroll
    for (int cb = 0; cb < 6; ++cb){
      bfrag o;
      #pragma unroll
      for (int j = 0; j < 8; ++j){
        const int c = cb*8 + j;
        o[j] = f2bs((xv[c]-m)*rs*ldT(g1, c0+c) + ldT(b1, c0+c));
      }
      *reinterpret_cast<bfrag*>(xr + cb*8) = o;
    }
  }
  // LN wrote own-wave rows; xa hoist reads own-wave rows -> wave-internal, no barrier.

  // ---- A-fragments to registers (xn then dead during head loop) ----
  bfrag xa[6];
  #pragma unroll
  for (int kt = 0; kt < 6; ++kt)
    xa[kt] = ldfrag(&xn[(w*16 + lr)*XN_S + kt*32 + lg*8]);

  // ---- mask class ids (row-class*3 + col-class), packed ----
  int cj[4], ci[4];
  #pragma unroll
  for (int ct = 0; ct < 4; ++ct){
    const int j = ct*16 + lr;
    cj[ct] = reg1(wi*8 + (j >> 3))*3 + reg1(wj*8 + (j & 7));
  }
  #pragma unroll
  for (int r = 0; r < 4; ++r){
    const int i = w*16 + lg*4 + r;
    ci[r] = reg1(wi*8 + (i >> 3))*3 + reg1(wj*8 + (i & 7));
  }

  int ohpk[6][2][2];

  // ---- QKV for head 0 (A regs, B from L2; no LDS) ----
  f32x4 acc[6];
  #pragma unroll
  for (int u = 0; u < 6; ++u) acc[u] = (f32x4){0.f,0.f,0.f,0.f};
  #pragma unroll
  for (int kt = 0; kt < 6; ++kt){
    bfrag bq[6];
    #pragma unroll
    for (int u = 0; u < 6; ++u){
      const int ctg = (u >> 1)*12 + (u & 1);          // head 0
      bq[u] = ldfrag(qkvwp + ((long long)(ctg*6 + kt)*64 + l)*8);
    }
    #pragma unroll
    for (int u = 0; u < 6; ++u) acc[u] = mm16(xa[kt], bq[u], acc[u]);
  }

  #pragma unroll
  for (int h = 0; h < 6; ++h){
    __syncthreads();                 // A: all waves' prev QKT/PV reads of qk/vt done
    // ---- store head-h QKV: Q (scaled) | K -> qk, V^T -> vt ----
    #pragma unroll
    for (int u = 0; u < 6; ++u){
      const int ctg = (u >> 1)*12 + 2*h + (u & 1);
      const float bia = ldT(qkvb, ctg*16 + lr);
      #pragma unroll
      for (int r = 0; r < 4; ++r){
        const int row = w*16 + lg*4 + r;
        const float v = acc[u][r] + bia;
        if (u < 2)      qk[row*QK_S + u*16 + lr] = f2b(v * 0.17677669529663687f);
        else if (u < 4) qk[row*QK_S + 32 + (u & 1)*16 + lr] = f2b(v);
        else            vt[((u & 1)*16 + lr)*VT_S + row] = f2b(v);
      }
    }
    __syncthreads();                 // B: qk/vt visible to all waves

    // ---- issue next head's QKV (overlaps QKT/softmax/PV below) ----
    if (h < 5){
      #pragma unroll
      for (int u = 0; u < 6; ++u) acc[u] = (f32x4){0.f,0.f,0.f,0.f};
      #pragma unroll
      for (int kt = 0; kt < 6; ++kt){
        bfrag bq[6];
        #pragma unroll
        for (int u = 0; u < 6; ++u){
          const int ctg = (u >> 1)*12 + 2*(h+1) + (u & 1);
          bq[u] = ldfrag(qkvwp + ((long long)(ctg*6 + kt)*64 + l)*8);
        }
        #pragma unroll
        for (int u = 0; u < 6; ++u) acc[u] = mm16(xa[kt], bq[u], acc[u]);
      }
    }

    // ---- QK^T ----
    f32x4 s4[4];
    {
      bfrag aq = ldfrag(&qk[(w*16 + lr)*QK_S + lg*8]);
      #pragma unroll
      for (int ct = 0; ct < 4; ++ct)
        s4[ct] = mm16(aq, ldfrag(&qk[(ct*16 + lr)*QK_S + 32 + lg*8]), (f32x4){0.f,0.f,0.f,0.f});
    }
    // ---- bias + mask + softmax; P -> xn (own rows, cols 0-63) ----
    const float* bh = bias6 + h*4096;
    #pragma unroll
    for (int r = 0; r < 4; ++r){
      const int i = w*16 + lg*4 + r;
      const int ib = i*64 + lr;
      float v[4];
      #pragma unroll
      for (int ct = 0; ct < 4; ++ct){
        const float msk = (ci[r] == cj[ct]) ? 0.f : -100.f;
        v[ct] = s4[ct][r] + bh[ib + ct*16] + msk;
      }
      float mx = rmax16(fmaxf(fmaxf(v[0],v[1]), fmaxf(v[2],v[3])));
      v[0] = __expf(v[0]-mx); v[1] = __expf(v[1]-mx);
      v[2] = __expf(v[2]-mx); v[3] = __expf(v[3]-mx);
      const float sm = rsum16(v[0]+v[1]+v[2]+v[3]);
      const float inv = __fdividef(1.f, sm);
      #pragma unroll
      for (int ct = 0; ct < 4; ++ct)
        xn[i*XN_S + ct*16 + lr] = f2b(v[ct]*inv);
    }
    // ---- PV (P own rows from xn; vt all rows, stored pre-B) ----
    f32x4 o2[2] = {(f32x4){0.f,0.f,0.f,0.f}, (f32x4){0.f,0.f,0.f,0.f}};
    #pragma unroll
    for (int ktp = 0; ktp < 2; ++ktp){
      bfrag ap = ldfrag(&xn[(w*16 + lr)*XN_S + ktp*32 + lg*8]);
      o2[0] = mm16(ap, ldfrag(&vt[(lr)*VT_S + ktp*32 + lg*8]), o2[0]);
      o2[1] = mm16(ap, ldfrag(&vt[(16 + lr)*VT_S + ktp*32 + lg*8]), o2[1]);
    }
    #pragma unroll
    for (int u = 0; u < 2; ++u){
      ohpk[h][u][0] = pk2(o2[u][0], o2[u][1]);
      ohpk[h][u][1] = pk2(o2[u][2], o2[u][3]);
    }
  }

  // ---- oh -> xn region (own rows; P dead) ----
  #pragma unroll
  for (int h = 0; h < 6; ++h)
    #pragma unroll
    for (int u = 0; u < 2; ++u)
      #pragma unroll
      for (int rr = 0; rr < 2; ++rr){
        const int pk = ohpk[h][u][rr];
        const int row = w*16 + lg*4 + rr*2;
        *reinterpret_cast<short*>(&xn[row*XN_S + h*32 + u*16 + lr]) = (short)(pk & 0xffff);
        *reinterpret_cast<short*>(&xn[(row+1)*XN_S + h*32 + u*16 + lr]) = (short)(((unsigned)pk) >> 16);
      }
  __syncthreads();                   // oh visible to all waves

  // ---- proj: wave -> (mp rows 32, chh 6 ct), K=192, B from L2 ----
  const int mp = w >> 1, chh = w & 1;
  f32x4 pacc[2][6];
  #pragma unroll
  for (int mt = 0; mt < 2; ++mt)
    #pragma unroll
    for (int cc = 0; cc < 6; ++cc) pacc[mt][cc] = (f32x4){0.f,0.f,0.f,0.f};
  #pragma unroll
  for (int kt = 0; kt < 6; ++kt){
    bfrag a0 = ldfrag(&xn[(mp*32 + lr)*XN_S + kt*32 + lg*8]);
    bfrag a1 = ldfrag(&xn[(mp*32 + 16 + lr)*XN_S + kt*32 + lg*8]);
    #pragma unroll
    for (int cc = 0; cc < 6; ++cc){
      bfrag bp = ldfrag(projwp + ((long long)((chh*6 + cc)*6 + kt)*64 + l)*8);
      pacc[0][cc] = mm16(a0, bp, pacc[0][cc]);
      pacc[1][cc] = mm16(a1, bp, pacc[1][cc]);
    }
  }
  // ---- epilogue: bias + residual + x2 store ----
  #pragma unroll
  for (int mt = 0; mt < 2; ++mt)
    #pragma unroll
    for (int r = 0; r < 4; ++r){
      const int t = mp*32 + mt*16 + lg*4 + r;
      const long long n = natidx(gw, t);
      #pragma unroll
      for (int cc = 0; cc < 6; ++cc){
        const int c = (chh*6 + cc)*16 + lr;
        const float y = pacc[mt][cc][r] + ldT(projb, c) + ldT(x, n*192 + c);
        if (x2f32) ((float*)(dout + n*768))[c] = y;
        else       ((bf16*)(dout + n*384))[c]  = f2b(y);
      }
    }
}

__global__ __launch_bounds__(256, 3) void swin_attn_k(
    const void* det, const void* x, const void* g1, const void* b1,
    const bf16* qkvwp, const void* qkvb, const bf16* projwp, const void* projb,
    const float* bias6, void* doutv)
{
  extern __shared__ char smem[];
  const bool isbf = (((const unsigned short*)det)[0] == 0x3F80u);
  char* dout = (char*)doutv;
  if (isbf)
    attn_body<bf16>((const bf16*)x, (const bf16*)g1, (const bf16*)b1, qkvwp,
                    (const bf16*)qkvb, projwp, (const bf16*)projb, bias6, dout, 0, smem);
  else
    attn_body<float>((const float*)x, (const float*)g1, (const float*)b1, qkvwp,
                     (const float*)qkvb, projwp, (const float*)projb, bias6, dout, 1, smem);
}

// ========== K3 MLP: 128 tokens/block, 4 waves, 12 chunks of 64 hidden ========
#define HS_S 72
#define LDS_K3 (48*512*2 + 128*HS_S*2)    // 49152 + 18432 = 67584 (xn2 51.2KB unioned)

template<typename T>
__device__ void mlp_body(const T* __restrict__ g2, const T* __restrict__ b2,
                         const bf16* __restrict__ fc1p, const T* __restrict__ fb1,
                         const bf16* __restrict__ fc2p, const T* __restrict__ fb2,
                         char* __restrict__ dout, int outf32, char* smem)
{
  bf16* xn2 = (bf16*)smem;            // [128][200] prologue only
  bf16* bw  = (bf16*)smem;            // [48*512] chunk weights
  bf16* hs  = bw + 48*512;            // [128][72]
  const int tid = threadIdx.x, l = tid & 63, w = tid >> 6;
  const int lr = l & 15, lg = l >> 4;
  const long long t0 = (long long)blockIdx.x * 128;

  // ---- LN2 on x2 slots (2 iters x 16 tokens/wave, quad-DPP) ----
  #pragma unroll
  for (int it = 0; it < 2; ++it){
    const int t = w*32 + it*16 + (l >> 2);
    const int c0 = (l & 3) * 48;
    const long long n = t0 + t;
    float xv[48];
    if (outf32) ld48((const float*)(dout + n*768), c0, xv);
    else        ld48((const bf16*)(dout + n*384), c0, xv);
    float s1 = 0.f, s2 = 0.f;
    #pragma unroll
    for (int i = 0; i < 48; ++i){ s1 += xv[i]; s2 = fmaf(xv[i], xv[i], s2); }
    s1 = rsum4(s1); s2 = rsum4(s2);
    const float m  = s1 * (1.f/192.f);
    const float rs = rsqrtf(s2*(1.f/192.f) - m*m + 1e-5f);
    bf16* xr = xn2 + t*XN_S + c0;
    #pragma unroll
    for (int cb = 0; cb < 6; ++cb){
      bfrag o;
      #pragma unroll
      for (int j = 0; j < 8; ++j){
        const int c = cb*8 + j;
        o[j] = f2bs((xv[c]-m)*rs*ldT(g2, c0+c) + ldT(b2, c0+c));
      }
      *reinterpret_cast<bfrag*>(xr + cb*8) = o;
    }
  }
  __syncthreads();

  bfrag xa[2][6];
  #pragma unroll
  for (int mt = 0; mt < 2; ++mt)
    #pragma unroll
    for (int kt = 0; kt < 6; ++kt)
      xa[mt][kt] = ldfrag(&xn2[(w*32 + mt*16 + lr)*XN_S + kt*32 + lg*8]);
  __syncthreads();                     // xn2 dead -> bw/hs region free

  f32x4 fa[2][12];
  #pragma unroll
  for (int mt = 0; mt < 2; ++mt)
    #pragma unroll
    for (int ct = 0; ct < 12; ++ct) fa[mt][ct] = (f32x4){0.f,0.f,0.f,0.f};

  for (int c = 0; c < 12; ++c){
    // ---- stage 48 frags (12/wave) via async global->LDS DMA, 0 VGPRs ----
    {
      const int q0 = w*12;
      #pragma unroll
      for (int e = 0; e < 12; ++e){
        const int q = q0 + e;
        const bf16* src = (q < 24)
          ? fc1p + ((long long)(c*24 + q)*64 + l)*8
          : fc2p + ((long long)(((q-24) >> 1)*24 + c*2 + ((q-24) & 1))*64 + l)*8;
        gload_lds16(src, bw + q*512);   // dst byte = q*1024 + lane*16
      }
    }
    __syncthreads();                    // drains vmcnt -> bw ready
    // fc1 (48 MFMA)
    f32x4 a1[2][4];
    #pragma unroll
    for (int mt = 0; mt < 2; ++mt)
      #pragma unroll
      for (int u = 0; u < 4; ++u) a1[mt][u] = (f32x4){0.f,0.f,0.f,0.f};
    #pragma unroll
    for (int kt = 0; kt < 6; ++kt)
      #pragma unroll
      for (int u = 0; u < 4; ++u){
        bfrag bq = ldfrag(&bw[((u*6 + kt)*64 + l)*8]);
        a1[0][u] = mm16(xa[0][kt], bq, a1[0][u]);
        a1[1][u] = mm16(xa[1][kt], bq, a1[1][u]);
      }
    // bias + GELU(sigmoid) -> hs (wave-private rows)
    #pragma unroll
    for (int u = 0; u < 4; ++u){
      const float bia = ldT(fb1, c*64 + u*16 + lr);
      #pragma unroll
      for (int mt = 0; mt < 2; ++mt)
        #pragma unroll
        for (int r = 0; r < 4; ++r){
          const float xv = a1[mt][u][r] + bia;
          const float g  = __fdividef(xv, 1.f + __expf(-1.702f*xv));
          hs[(w*32 + mt*16 + lg*4 + r)*HS_S + u*16 + lr] = f2b(g);
        }
    }
    // fc2 (48 MFMA)
    #pragma unroll
    for (int ktl = 0; ktl < 2; ++ktl){
      bfrag aH0 = ldfrag(&hs[(w*32 + lr)*HS_S + ktl*32 + lg*8]);
      bfrag aH1 = ldfrag(&hs[(w*32 + 16 + lr)*HS_S + ktl*32 + lg*8]);
      #pragma unroll
      for (int ct = 0; ct < 12; ++ct){
        bfrag bq = ldfrag(&bw[((24 + ct*2 + ktl)*64 + l)*8]);
        fa[0][ct] = mm16(aH0, bq, fa[0][ct]);
        fa[1][ct] = mm16(aH1, bq, fa[1][ct]);
      }
    }
    __syncthreads();                   // bw reads done before next stage
  }

  // ---- epilogue: + fb2 + residual(x2 slot) -> final out (in-place) ----
  #pragma unroll
  for (int mt = 0; mt < 2; ++mt)
    #pragma unroll
    for (int r = 0; r < 4; ++r){
      const long long n = t0 + w*32 + mt*16 + lg*4 + r;
      #pragma unroll
      for (int ct = 0; ct < 12; ++ct){
        const int cc = ct*16 + lr;
        float resid = outf32 ? ((const float*)(dout + n*768))[cc]
                             : b2f(((const bf16*)(dout + n*384))[cc]);
        const float y = fa[mt][ct][r] + ldT(fb2, cc) + resid;
        if (outf32) ((float*)(dout + n*768))[cc] = y;
        else        ((bf16*)(dout + n*384))[cc]  = f2b(y);
      }
    }
}

__global__ __launch_bounds__(256, 2) void swin_mlp_k(
    const void* det, const void* g2, const void* b2, const bf16* fc1p, const void* fb1,
    const bf16* fc2p, const void* fb2, void* doutv)
{
  extern __shared__ char smem[];
  const bool isbf = (((const unsigned short*)det)[0] == 0x3F80u);
  char* dout = (char*)doutv;
  if (isbf)
    mlp_body<bf16>((const bf16*)g2, (const bf16*)b2, fc1p, (const bf16*)fb1,
                   fc2p, (const bf16*)fb2, dout, 0, smem);
  else
    mlp_body<float>((const float*)g2, (const float*)b2, fc1p, (const float*)fb1,
                    fc2p, (const float*)fb2, dout, 1, smem);
}

extern "C" void kernel_launch(void* const* d_in, const int* in_sizes, int n_in,
                              void* d_out, int out_size, void* d_ws, size_t ws_size,
                              hipStream_t stream)
{
  (void)in_sizes; (void)n_in; (void)out_size; (void)ws_size;
  char* ws = (char*)d_ws;

  (void)hipFuncSetAttribute((const void*)swin_attn_k, hipFuncAttributeMaxDynamicSharedMemorySize, LDS_K1);
  (void)hipFuncSetAttribute((const void*)swin_mlp_k,  hipFuncAttributeMaxDynamicSharedMemorySize, LDS_K3);

  prep_k<<<dim3(312), dim3(256), 0, stream>>>(
      d_in[1], d_in[3], d_in[6], d_in[10], d_in[12], d_in[5], (const int*)d_in[15], ws);

  swin_attn_k<<<dim3(2048), dim3(256), LDS_K1, stream>>>(
      d_in[1], d_in[0], d_in[1], d_in[2],
      (const bf16*)(ws + WS_QKV), d_in[4], (const bf16*)(ws + WS_PROJ), d_in[7],
      (const float*)(ws + WS_BIAS6), d_out);

  swin_mlp_k<<<dim3(1024), dim3(256), LDS_K3, stream>>>(
      d_in[1], d_in[8], d_in[9],
      (const bf16*)(ws + WS_FC1), d_in[11], (const bf16*)(ws + WS_FC2), d_in[13], d_out);
}